// Round 3
// baseline (40.012 us; speedup 1.0000x reference)
//
#include <hip/hip_runtime.h>

#define NB 4
#define SS 256
#define DM 128
#define NH 8
#define HD 16
#define DDim 64
#define TT 257
#define NPOS (NB*TT)   // 1028

// workspace float offsets
#define OFF_SQ  2080     // 32*257
#define OFF_SK  10304    // 32*257
#define OFF_G   18528    // 16*257
#define OFF_V   22640    // 32*257*16
#define ATT_BASE (NB*TT*NH*HD)   // 131584

// ---------------- Kernel 1: fused projections (V, sq, sk, G) ----------------
// grid 257 blocks x 256 threads; block = 4 positions.
// thread = (ph = tid>>7 -> 2 positions, c = tid&127 channel)
__global__ __launch_bounds__(256) void proj_kernel(
    const float* __restrict__ de, const float* __restrict__ nve,
    const float* __restrict__ Wq, const float* __restrict__ bq,
    const float* __restrict__ Wk, const float* __restrict__ bk,
    const float* __restrict__ Wv, const float* __restrict__ bv,
    const float* __restrict__ aw, float* __restrict__ ws)
{
  __shared__ float4 xs4[4][32];
  int tid = threadIdx.x;
  int pos0 = blockIdx.x * 4;
  if (tid < 128) {
    int lp = tid >> 5, e4 = tid & 31;
    xs4[lp][e4] = ((const float4*)nve)[(pos0 + lp)*32 + e4];
  }
  __syncthreads();

  int c = tid & 127, ph = tid >> 7;
  int dd = c & 15, h = c >> 4;
  const float4* wq4 = (const float4*)(Wq + c*DM);
  const float4* wk4 = (const float4*)(Wk + c*DM);
  const float4* wv4 = (const float4*)(Wv + c*DM);
  float aqd = aw[dd], akd = aw[16 + dd];

  float accq[2] = {bq[c], bq[c]};
  float acck[2] = {bk[c], bk[c]};
  float accv[2] = {bv[c], bv[c]};

  #pragma unroll 4
  for (int e4 = 0; e4 < 32; ++e4) {
    float4 wq = wq4[e4], wk = wk4[e4], wv = wv4[e4];
    #pragma unroll
    for (int p = 0; p < 2; ++p) {
      float4 x = xs4[ph*2 + p][e4];
      accq[p] += wq.x*x.x + wq.y*x.y + wq.z*x.z + wq.w*x.w;
      acck[p] += wk.x*x.x + wk.y*x.y + wk.z*x.z + wk.w*x.w;
      accv[p] += wv.x*x.x + wv.y*x.y + wv.z*x.z + wv.w*x.w;
    }
  }

  #pragma unroll
  for (int p = 0; p < 2; ++p) {
    int pos = pos0 + ph*2 + p;
    int b = pos / TT, t = pos - b*TT;
    ws[OFF_V + ((b*NH + h)*TT + t)*HD + dd] = accv[p];
    float vq = accq[p] * aqd, vk = acck[p] * akd;
    vq += __shfl_xor(vq, 1); vq += __shfl_xor(vq, 2);
    vq += __shfl_xor(vq, 4); vq += __shfl_xor(vq, 8);
    vk += __shfl_xor(vk, 1); vk += __shfl_xor(vk, 2);
    vk += __shfl_xor(vk, 4); vk += __shfl_xor(vk, 8);
    if (dd == 0) {
      ws[OFF_SQ + (b*NH + h)*TT + t] = vq;
      ws[OFF_SK + (b*NH + h)*TT + t] = vk;
    }
  }

  // G table: 16*257 entries over 257 blocks -> 16 per block
  if (tid < 16) {
    int gi = blockIdx.x * 16 + tid;           // 0..4111, gi = bm*TT + t
    int bm = gi / TT, t = gi - bm*TT;
    float val = 0.f;
    if (t > 0) {
      int b = bm >> 2, m = bm & 3;
      const float* dp = de + (b*SS + (t-1))*DDim + m*16;
      #pragma unroll
      for (int d = 0; d < 16; ++d) val += dp[d] * aw[32 + d];
    }
    ws[OFF_G + gi] = val;
  }
}

// ---------------- Kernel 2: attention, V/sk/G staged in LDS ----------------
// grid = 32 bh * 33 rowblocks = 1056 blocks x 256; 8 rows/block, 2 per wave
__global__ __launch_bounds__(256) void attn_kernel(
    const float* __restrict__ ws, const float* __restrict__ ab_ptr,
    float* __restrict__ out)
{
  __shared__ float4 v_lds4[TT*4];            // V[bh]: 4112 floats
  __shared__ float u_lds[TT+3];              // sk
  __shared__ float g_lds[TT+3];              // G[b, h&3]
  __shared__ float p_lds[4][260];
  const float* v_lds = (const float*)v_lds4;

  int tid  = threadIdx.x;
  int wave = tid >> 6, lane = tid & 63;
  int rb = blockIdx.x % 33;
  int bh = blockIdx.x / 33;
  int h = bh & 7, b = bh >> 3;
  float ab = ab_ptr[0];

  const float4* v4  = (const float4*)(ws + OFF_V + bh*TT*HD);
  const float* skp  = ws + OFF_SK + bh*TT;
  const float* gp   = ws + OFF_G + (b*4 + (h & 3))*TT;

  #pragma unroll
  for (int r = 0; r < 5; ++r) {
    int idx = tid + r*256;
    if (idx < TT*4) v_lds4[idx] = v4[idx];
  }
  for (int j = tid; j < TT; j += 256) { u_lds[j] = skp[j]; g_lds[j] = gp[j]; }
  __syncthreads();

  bool hlo = (h < 4);
  for (int rr = 0; rr < 2; ++rr) {
    int i = rb*8 + rr*4 + wave;
    if (i >= TT) break;

    float Ci = ws[OFF_SQ + bh*TT + i] + ab;
    if (i > 0 && hlo) Ci += g_lds[i];          // row edge term (low heads)
    bool colg = (!hlo) || (i == 0);            // column edge term applies

    float l[4];
    float lm = -3.0e38f;
    #pragma unroll
    for (int k = 0; k < 4; ++k) {
      int j = lane + 64*k;
      float u = u_lds[j] + (colg ? g_lds[j] : 0.f);
      l[k] = Ci + u;
      bool msk = (j == 0) || (i > 0 && j == i);
      if (!msk) lm = fmaxf(lm, l[k]);
    }
    float l4 = 0.f; bool has4 = false;
    if (lane == 0) {
      l4 = Ci + u_lds[256] + (colg ? g_lds[256] : 0.f);
      if (i != 256) { lm = fmaxf(lm, l4); has4 = true; }
    }
    #pragma unroll
    for (int off = 1; off < 64; off <<= 1) lm = fmaxf(lm, __shfl_xor(lm, off));

    float p[4], ps = 0.f;
    #pragma unroll
    for (int k = 0; k < 4; ++k) {
      int j = lane + 64*k;
      bool msk = (j == 0) || (i > 0 && j == i);
      p[k] = msk ? 0.f : __expf(l[k] - lm);
      ps += p[k];
    }
    float p4 = has4 ? __expf(l4 - lm) : 0.f;
    ps += p4;
    #pragma unroll
    for (int off = 1; off < 64; off <<= 1) ps += __shfl_xor(ps, off);
    float inv = 1.0f / ps;

    float* arow = out + ATT_BASE + (bh*TT + i)*TT;
    #pragma unroll
    for (int k = 0; k < 4; ++k) {
      float v = p[k] * inv;
      arow[lane + 64*k] = v;
      p_lds[wave][lane + 64*k] = v;
    }
    if (lane == 0) { float v = p4 * inv; arow[256] = v; p_lds[wave][256] = v; }

    // ctx[d] = sum_j p[j]*V[j,d], all from LDS (same-wave, no barrier)
    int g = lane >> 4, d = lane & 15;
    float acc = 0.f;
    #pragma unroll 8
    for (int it = 0; it < 64; ++it) {
      int jj = g + 4*it;
      acc += p_lds[wave][jj] * v_lds[jj*HD + d];
    }
    if (g == 0) acc += p_lds[wave][256] * v_lds[256*HD + d];
    acc += __shfl_xor(acc, 16);
    acc += __shfl_xor(acc, 32);
    if (lane < 16)
      out[((b*TT + i)*NH + h)*HD + lane] = acc;
  }
}

extern "C" void kernel_launch(void* const* d_in, const int* in_sizes, int n_in,
                              void* d_out, int out_size, void* d_ws, size_t ws_size,
                              hipStream_t stream) {
  const float* de  = (const float*)d_in[0];
  const float* nve = (const float*)d_in[1];
  const float* Wq  = (const float*)d_in[2];
  const float* bq  = (const float*)d_in[3];
  const float* Wk  = (const float*)d_in[4];
  const float* bk  = (const float*)d_in[5];
  const float* Wv  = (const float*)d_in[6];
  const float* bv  = (const float*)d_in[7];
  const float* aw  = (const float*)d_in[8];
  const float* ab  = (const float*)d_in[9];
  float* out = (float*)d_out;
  float* ws  = (float*)d_ws;

  proj_kernel<<<NPOS/4, 256, 0, stream>>>(de, nve, Wq, bq, Wk, bk, Wv, bv, aw, ws);
  attn_kernel<<<32*33, 256, 0, stream>>>(ws, ab, out);
}

// Round 4
// 38.075 us; speedup vs baseline: 1.0509x; 1.0509x over previous
//
#include <hip/hip_runtime.h>

#define NB 4
#define SS 256
#define DM 128
#define NH 8
#define HD 16
#define DDim 64
#define TT 257
#define NPOS (NB*TT)   // 1028

// workspace float offsets
#define OFF_SQ  2080     // 32*257
#define OFF_SK  10304    // 32*257
#define OFF_G   18528    // 16*257
#define OFF_V   22640    // 32*257*16
#define ATT_BASE (NB*TT*NH*HD)   // 131584

// DPP / swizzle helpers (all ctrl values are compile-time literals)
#define DPPF(x, ctrl) __int_as_float(__builtin_amdgcn_update_dpp(0, __float_as_int(x), (ctrl), 0xf, 0xf, true))
#define SWZF(x, off)  __int_as_float(__builtin_amdgcn_ds_swizzle(__float_as_int(x), (off)))

__device__ __forceinline__ float wred_max(float x) {
  x = fmaxf(x, DPPF(x, 0xB1));   // quad_perm [1,0,3,2]  == xor1
  x = fmaxf(x, DPPF(x, 0x4E));   // quad_perm [2,3,0,1]  == xor2
  x = fmaxf(x, DPPF(x, 0x141));  // row_half_mirror      == xor4 (post 1,2)
  x = fmaxf(x, DPPF(x, 0x140));  // row_mirror           == xor8 (post 1,2,4)
  x = fmaxf(x, SWZF(x, 0x401F)); // ds_swizzle xor16
  x = fmaxf(x, __shfl_xor(x, 32));
  return x;
}
__device__ __forceinline__ float wred_sum(float x) {
  x += DPPF(x, 0xB1);
  x += DPPF(x, 0x4E);
  x += DPPF(x, 0x141);
  x += DPPF(x, 0x140);
  x += SWZF(x, 0x401F);
  x += __shfl_xor(x, 32);
  return x;
}
// reduce over jjlo (lane bits 2..5), preserving dq (bits 0..1)
__device__ __forceinline__ float red_jj(float x) {
  x += DPPF(x, 0x124);           // row_ror:4  (ring over jjlo within 16-row)
  x += DPPF(x, 0x128);           // row_ror:8
  x += SWZF(x, 0x401F);          // xor16
  x += __shfl_xor(x, 32);        // xor32
  return x;
}

// ---------------- Kernel 1: fused projections (V, sq, sk, G) ----------------
__global__ __launch_bounds__(256) void proj_kernel(
    const float* __restrict__ de, const float* __restrict__ nve,
    const float* __restrict__ Wq, const float* __restrict__ bq,
    const float* __restrict__ Wk, const float* __restrict__ bk,
    const float* __restrict__ Wv, const float* __restrict__ bv,
    const float* __restrict__ aw, float* __restrict__ ws)
{
  __shared__ float4 xs4[4][32];
  int tid = threadIdx.x;
  int pos0 = blockIdx.x * 4;
  if (tid < 128) {
    int lp = tid >> 5, e4 = tid & 31;
    xs4[lp][e4] = ((const float4*)nve)[(pos0 + lp)*32 + e4];
  }
  __syncthreads();

  int c = tid & 127, ph = tid >> 7;
  int dd = c & 15, h = c >> 4;
  const float4* wq4 = (const float4*)(Wq + c*DM);
  const float4* wk4 = (const float4*)(Wk + c*DM);
  const float4* wv4 = (const float4*)(Wv + c*DM);
  float aqd = aw[dd], akd = aw[16 + dd];

  float accq[2] = {bq[c], bq[c]};
  float acck[2] = {bk[c], bk[c]};
  float accv[2] = {bv[c], bv[c]};

  #pragma unroll 4
  for (int e4 = 0; e4 < 32; ++e4) {
    float4 wq = wq4[e4], wk = wk4[e4], wv = wv4[e4];
    #pragma unroll
    for (int p = 0; p < 2; ++p) {
      float4 x = xs4[ph*2 + p][e4];
      accq[p] += wq.x*x.x + wq.y*x.y + wq.z*x.z + wq.w*x.w;
      acck[p] += wk.x*x.x + wk.y*x.y + wk.z*x.z + wk.w*x.w;
      accv[p] += wv.x*x.x + wv.y*x.y + wv.z*x.z + wv.w*x.w;
    }
  }

  #pragma unroll
  for (int p = 0; p < 2; ++p) {
    int pos = pos0 + ph*2 + p;
    int b = pos / TT, t = pos - b*TT;
    ws[OFF_V + ((b*NH + h)*TT + t)*HD + dd] = accv[p];
    float vq = accq[p] * aqd, vk = acck[p] * akd;
    vq += __shfl_xor(vq, 1); vq += __shfl_xor(vq, 2);
    vq += __shfl_xor(vq, 4); vq += __shfl_xor(vq, 8);
    vk += __shfl_xor(vk, 1); vk += __shfl_xor(vk, 2);
    vk += __shfl_xor(vk, 4); vk += __shfl_xor(vk, 8);
    if (dd == 0) {
      ws[OFF_SQ + (b*NH + h)*TT + t] = vq;
      ws[OFF_SK + (b*NH + h)*TT + t] = vk;
    }
  }

  if (tid < 16) {
    int gi = blockIdx.x * 16 + tid;
    int bm = gi / TT, t = gi - bm*TT;
    float val = 0.f;
    if (t > 0) {
      int b = bm >> 2, m = bm & 3;
      const float* dp = de + (b*SS + (t-1))*DDim + m*16;
      #pragma unroll
      for (int d = 0; d < 16; ++d) val += dp[d] * aw[32 + d];
    }
    ws[OFF_G + gi] = val;
  }
}

// ---------------- Kernel 2: attention, 4 rows/wave, b128 outer-product ctx --
// grid = 32 bh * 17 rowblocks = 544 blocks x 256 (4 waves x 4 rows = 16 rows)
__global__ __launch_bounds__(256) void attn_kernel(
    const float* __restrict__ ws, const float* __restrict__ ab_ptr,
    float* __restrict__ out)
{
  __shared__ float4 v_lds[272*4];      // V rows 0..271 (tail zeroed), 64B/row
  __shared__ float4 p4_lds[4][272];    // per-wave packed p (4 rows per float4)
  __shared__ float u_lds[260];         // sk (+G if h>=4)
  __shared__ float g_lds[260];         // G[b, h&3]

  int tid  = threadIdx.x;
  int wave = tid >> 6, lane = tid & 63;
  int rb = blockIdx.x % 17;
  int bh = blockIdx.x / 17;
  int h = bh & 7, b = bh >> 3;
  bool hge = (h >= 4);

  // ---- staging ----
  const float4* v4 = (const float4*)(ws + OFF_V + bh*TT*HD);
  const float* skp = ws + OFF_SK + bh*TT;
  const float* gp  = ws + OFF_G + (b*4 + (h & 3))*TT;
  for (int idx = tid; idx < 272*4; idx += 256)
    v_lds[idx] = (idx < TT*4) ? v4[idx] : make_float4(0.f,0.f,0.f,0.f);
  for (int j = tid; j < 260; j += 256) {
    float g = (j < TT) ? gp[j]  : 0.f;
    float u = (j < TT) ? skp[j] : 0.f;
    u_lds[j] = u + (hge ? g : 0.f);
    g_lds[j] = g;
  }
  __syncthreads();

  float ab = ab_ptr[0];
  int i0 = rb*16 + wave*4;
  bool ext0 = (i0 == 0) && !hge;   // row 0 of wave is CLS with low head

  float Ci[4]; bool valid[4];
  #pragma unroll
  for (int r = 0; r < 4; ++r) {
    int i = i0 + r;
    valid[r] = (i < TT);
    int ic = valid[r] ? i : 256;
    Ci[r] = ws[OFF_SQ + bh*TT + ic] + ab;
    if (!hge && i > 0) Ci[r] += g_lds[ic];   // row edge term (low heads)
  }

  // ---- logits + max ----
  float l[4][4];
  float mx[4] = {-3.0e38f, -3.0e38f, -3.0e38f, -3.0e38f};
  #pragma unroll
  for (int k = 0; k < 4; ++k) {
    int j = lane + 64*k;
    float base = u_lds[j];
    float gv = 0.f;
    if (ext0) gv = g_lds[j];
    #pragma unroll
    for (int r = 0; r < 4; ++r) {
      int i = i0 + r;
      float lv = Ci[r] + base;
      if (r == 0 && ext0) lv += gv;
      bool msk = (j == 0) || (i > 0 && j == i);
      l[r][k] = msk ? -3.0e38f : lv;
      mx[r] = fmaxf(mx[r], l[r][k]);
    }
  }
  float lt[4] = {-3.0e38f, -3.0e38f, -3.0e38f, -3.0e38f};
  if (lane == 0) {                       // tail column j = 256
    float base = u_lds[256];
    float gv = ext0 ? g_lds[256] : 0.f;
    #pragma unroll
    for (int r = 0; r < 4; ++r) {
      int i = i0 + r;
      float lv = Ci[r] + base;
      if (r == 0 && ext0) lv += gv;
      lt[r] = (i == 256) ? -3.0e38f : lv;
      mx[r] = fmaxf(mx[r], lt[r]);
    }
  }
  #pragma unroll
  for (int r = 0; r < 4; ++r) mx[r] = wred_max(mx[r]);

  // ---- exp + sum ----
  float pn[4][4];
  float s[4] = {0.f,0.f,0.f,0.f};
  #pragma unroll
  for (int r = 0; r < 4; ++r) {
    #pragma unroll
    for (int k = 0; k < 4; ++k) {
      float p = __expf(l[r][k] - mx[r]);   // masked -> exp(-3e38) == 0
      pn[r][k] = p;
      s[r] += p;
    }
  }
  float pt[4] = {0.f,0.f,0.f,0.f};
  if (lane == 0) {
    #pragma unroll
    for (int r = 0; r < 4; ++r) { pt[r] = __expf(lt[r] - mx[r]); s[r] += pt[r]; }
  }
  float inv[4];
  #pragma unroll
  for (int r = 0; r < 4; ++r) inv[r] = 1.0f / wred_sum(s[r]);

  // ---- normalize, store attn, pack p4 ----
  #pragma unroll
  for (int k = 0; k < 4; ++k) {
    int j = lane + 64*k;
    #pragma unroll
    for (int r = 0; r < 4; ++r) {
      pn[r][k] *= inv[r];
      if (valid[r]) out[ATT_BASE + (bh*TT + (i0+r))*TT + j] = pn[r][k];
    }
    p4_lds[wave][j] = make_float4(pn[0][k], pn[1][k], pn[2][k], pn[3][k]);
  }
  if (lane == 0) {
    float4 t4;
    float* tp = (float*)&t4;
    #pragma unroll
    for (int r = 0; r < 4; ++r) {
      tp[r] = pt[r] * inv[r];
      if (valid[r]) out[ATT_BASE + (bh*TT + (i0+r))*TT + 256] = tp[r];
    }
    p4_lds[wave][256] = t4;
  }
  if (lane >= 1 && lane < 16)
    p4_lds[wave][256 + lane] = make_float4(0.f,0.f,0.f,0.f);
  __syncthreads();   // order p4 writes before cross-lane reads (also uniform)

  // ---- ctx: outer-product over 16-column chunks ----
  int jjlo = lane >> 2, dq = lane & 3;
  float4 acc0 = {0,0,0,0}, acc1 = {0,0,0,0}, acc2 = {0,0,0,0}, acc3 = {0,0,0,0};
  #pragma unroll
  for (int it = 0; it < 17; ++it) {
    int jj = it*16 + jjlo;
    float4 v = v_lds[jj*4 + dq];
    float4 p = p4_lds[wave][jj];
    acc0.x += p.x*v.x; acc0.y += p.x*v.y; acc0.z += p.x*v.z; acc0.w += p.x*v.w;
    acc1.x += p.y*v.x; acc1.y += p.y*v.y; acc1.z += p.y*v.z; acc1.w += p.y*v.w;
    acc2.x += p.z*v.x; acc2.y += p.z*v.y; acc2.z += p.z*v.z; acc2.w += p.z*v.w;
    acc3.x += p.w*v.x; acc3.y += p.w*v.y; acc3.z += p.w*v.z; acc3.w += p.w*v.w;
  }
  float4 accs[4] = {acc0, acc1, acc2, acc3};
  #pragma unroll
  for (int r = 0; r < 4; ++r) {
    accs[r].x = red_jj(accs[r].x);
    accs[r].y = red_jj(accs[r].y);
    accs[r].z = red_jj(accs[r].z);
    accs[r].w = red_jj(accs[r].w);
  }
  if (lane < 4) {   // lane == dq, jjlo == 0
    #pragma unroll
    for (int r = 0; r < 4; ++r) {
      if (valid[r])
        *(float4*)(out + ((b*TT + (i0+r))*NH + h)*HD + lane*4) = accs[r];
    }
  }
}

extern "C" void kernel_launch(void* const* d_in, const int* in_sizes, int n_in,
                              void* d_out, int out_size, void* d_ws, size_t ws_size,
                              hipStream_t stream) {
  const float* de  = (const float*)d_in[0];
  const float* nve = (const float*)d_in[1];
  const float* Wq  = (const float*)d_in[2];
  const float* bq  = (const float*)d_in[3];
  const float* Wk  = (const float*)d_in[4];
  const float* bk  = (const float*)d_in[5];
  const float* Wv  = (const float*)d_in[6];
  const float* bv  = (const float*)d_in[7];
  const float* aw  = (const float*)d_in[8];
  const float* ab  = (const float*)d_in[9];
  float* out = (float*)d_out;
  float* ws  = (float*)d_ws;

  proj_kernel<<<NPOS/4, 256, 0, stream>>>(de, nve, Wq, bq, Wk, bk, Wv, bv, aw, ws);
  attn_kernel<<<32*17, 256, 0, stream>>>(ws, ab, out);
}

// Round 5
// 31.939 us; speedup vs baseline: 1.2528x; 1.1921x over previous
//
#include <hip/hip_runtime.h>

#define NB 4
#define SS 256
#define DM 128
#define NH 8
#define HD 16
#define DDim 64
#define TT 257
#define NPOS (NB*TT)   // 1028

// workspace float offsets
#define OFF_WQE 0        // 8*128
#define OFF_WKE 1024     // 8*128
#define OFF_BQE 2048     // 8 (padded)
#define OFF_BKE 2064     // 8 (padded)
#define OFF_SQ  2080     // 32*257
#define OFF_SK  10304    // 32*257
#define OFF_G   18528    // 16*257
#define OFF_V   22640    // 32*257*16
#define ATT_BASE (NB*TT*NH*HD)   // 131584

// DPP / swizzle helpers
#define DPPF(x, ctrl) __int_as_float(__builtin_amdgcn_update_dpp(0, __float_as_int(x), (ctrl), 0xf, 0xf, true))
#define SWZF(x, off)  __int_as_float(__builtin_amdgcn_ds_swizzle(__float_as_int(x), (off)))

__device__ __forceinline__ float wred_max(float x) {
  x = fmaxf(x, DPPF(x, 0xB1));   // xor1
  x = fmaxf(x, DPPF(x, 0x4E));   // xor2
  x = fmaxf(x, DPPF(x, 0x141));  // xor4
  x = fmaxf(x, DPPF(x, 0x140));  // xor8
  x = fmaxf(x, SWZF(x, 0x401F)); // xor16
  x = fmaxf(x, __shfl_xor(x, 32));
  return x;
}
__device__ __forceinline__ float wred_sum(float x) {
  x += DPPF(x, 0xB1);
  x += DPPF(x, 0x4E);
  x += DPPF(x, 0x141);
  x += DPPF(x, 0x140);
  x += SWZF(x, 0x401F);
  x += __shfl_xor(x, 32);
  return x;
}
__device__ __forceinline__ float red_jj(float x) {
  x += DPPF(x, 0x124);           // row_ror:4
  x += DPPF(x, 0x128);           // row_ror:8
  x += SWZF(x, 0x401F);          // xor16
  x += __shfl_xor(x, 32);        // xor32
  return x;
}

// ---------------- Kernel A: setup (eff weights + G table) [R2 verbatim] ----
__global__ __launch_bounds__(256) void setup_kernel(
    const float* __restrict__ de,
    const float* __restrict__ Wq, const float* __restrict__ bq,
    const float* __restrict__ Wk, const float* __restrict__ bk,
    const float* __restrict__ aw, float* __restrict__ ws)
{
  int tid = threadIdx.x, bid = blockIdx.x;
  if (bid < 4) {
    int idx = bid*256 + tid;       // 0..1023
    int h = idx >> 7, e = idx & 127;
    float sq_ = 0.f, sk_ = 0.f;
    #pragma unroll
    for (int d = 0; d < 16; ++d) {
      sq_ += Wq[(h*16+d)*DM + e] * aw[d];
      sk_ += Wk[(h*16+d)*DM + e] * aw[16+d];
    }
    ws[OFF_WQE + idx] = sq_;
    ws[OFF_WKE + idx] = sk_;
    if (bid == 0 && tid < 16) {
      int hh = tid & 7; bool isq = (tid < 8);
      float s = 0.f;
      #pragma unroll
      for (int d = 0; d < 16; ++d)
        s += isq ? bq[hh*16+d]*aw[d] : bk[hh*16+d]*aw[16+d];
      ws[(isq ? OFF_BQE : OFF_BKE) + hh] = s;
    }
  } else {
    int chunk = (bid - 4) * 1028;
    int lim = chunk + 1028;
    for (int r = 0; r < 5; ++r) {
      int gi = chunk + tid + r*256;
      if (gi < lim && gi < 16*TT) {
        int bm = gi / TT, t = gi - bm*TT;
        float val = 0.f;
        if (t > 0) {
          int b = bm >> 2, m = bm & 3;
          const float* dp = de + (b*SS + (t-1))*DDim + m*16;
          #pragma unroll
          for (int d = 0; d < 16; ++d) val += dp[d] * aw[32+d];
        }
        ws[OFF_G + gi] = val;
      }
    }
  }
}

// ---------------- Kernel B: projections (V + sq + sk) [R2 verbatim] --------
__global__ __launch_bounds__(256) void proj_kernel(
    const float* __restrict__ nve,
    const float* __restrict__ Wv, const float* __restrict__ bv,
    float* __restrict__ ws)
{
  __shared__ float4 xs4[16][32];
  int tid = threadIdx.x;
  int pos0 = blockIdx.x * 16;
  const float4* nve4 = (const float4*)nve;
  for (int idx = tid; idx < 512; idx += 256) {
    int lp = idx >> 5, e4 = idx & 31;
    int pos = pos0 + lp;
    xs4[lp][e4] = (pos < NPOS) ? nve4[pos*32 + e4] : make_float4(0.f,0.f,0.f,0.f);
  }
  __syncthreads();

  int c = tid & 127, ph = tid >> 7;
  const float4* wv4 = (const float4*)(Wv + c*DM);
  bool doe = (c < 16);
  const float4* we4 = doe
      ? (const float4*)(ws + (c < 8 ? OFF_WQE + c*DM : OFF_WKE + (c-8)*DM))
      : wv4;

  float acc[8]  = {0.f,0.f,0.f,0.f,0.f,0.f,0.f,0.f};
  float acce[8] = {0.f,0.f,0.f,0.f,0.f,0.f,0.f,0.f};

  #pragma unroll 4
  for (int e4 = 0; e4 < 32; ++e4) {
    float4 w = wv4[e4];
    #pragma unroll
    for (int p = 0; p < 8; ++p) {
      float4 x = xs4[ph*8+p][e4];
      acc[p] += w.x*x.x + w.y*x.y + w.z*x.z + w.w*x.w;
    }
    if (doe) {
      float4 we = we4[e4];
      #pragma unroll
      for (int p = 0; p < 8; ++p) {
        float4 x = xs4[ph*8+p][e4];
        acce[p] += we.x*x.x + we.y*x.y + we.z*x.z + we.w*x.w;
      }
    }
  }

  int h = c >> 4, d = c & 15;
  float bvc = bv[c];
  float be  = doe ? ws[(c < 8 ? OFF_BQE + c : OFF_BKE + (c-8))] : 0.f;
  for (int p = 0; p < 8; ++p) {
    int pos = pos0 + ph*8 + p;
    if (pos >= NPOS) break;
    int b = pos / TT, t = pos - b*TT;
    ws[OFF_V + ((b*NH + h)*TT + t)*HD + d] = acc[p] + bvc;
    if (c < 8)       ws[OFF_SQ + (b*NH + c)*TT + t]     = acce[p] + be;
    else if (c < 16) ws[OFF_SK + (b*NH + (c-8))*TT + t] = acce[p] + be;
  }
}

// ---------------- Kernel C: attention [R4 verbatim] ------------------------
// grid = 32 bh * 17 rowblocks = 544 blocks x 256 (4 waves x 4 rows = 16 rows)
__global__ __launch_bounds__(256) void attn_kernel(
    const float* __restrict__ ws, const float* __restrict__ ab_ptr,
    float* __restrict__ out)
{
  __shared__ float4 v_lds[272*4];
  __shared__ float4 p4_lds[4][272];
  __shared__ float u_lds[260];
  __shared__ float g_lds[260];

  int tid  = threadIdx.x;
  int wave = tid >> 6, lane = tid & 63;
  int rb = blockIdx.x % 17;
  int bh = blockIdx.x / 17;
  int h = bh & 7, b = bh >> 3;
  bool hge = (h >= 4);

  const float4* v4 = (const float4*)(ws + OFF_V + bh*TT*HD);
  const float* skp = ws + OFF_SK + bh*TT;
  const float* gp  = ws + OFF_G + (b*4 + (h & 3))*TT;
  for (int idx = tid; idx < 272*4; idx += 256)
    v_lds[idx] = (idx < TT*4) ? v4[idx] : make_float4(0.f,0.f,0.f,0.f);
  for (int j = tid; j < 260; j += 256) {
    float g = (j < TT) ? gp[j]  : 0.f;
    float u = (j < TT) ? skp[j] : 0.f;
    u_lds[j] = u + (hge ? g : 0.f);
    g_lds[j] = g;
  }
  __syncthreads();

  float ab = ab_ptr[0];
  int i0 = rb*16 + wave*4;
  bool ext0 = (i0 == 0) && !hge;

  float Ci[4]; bool valid[4];
  #pragma unroll
  for (int r = 0; r < 4; ++r) {
    int i = i0 + r;
    valid[r] = (i < TT);
    int ic = valid[r] ? i : 256;
    Ci[r] = ws[OFF_SQ + bh*TT + ic] + ab;
    if (!hge && i > 0) Ci[r] += g_lds[ic];
  }

  float l[4][4];
  float mx[4] = {-3.0e38f, -3.0e38f, -3.0e38f, -3.0e38f};
  #pragma unroll
  for (int k = 0; k < 4; ++k) {
    int j = lane + 64*k;
    float base = u_lds[j];
    float gv = 0.f;
    if (ext0) gv = g_lds[j];
    #pragma unroll
    for (int r = 0; r < 4; ++r) {
      int i = i0 + r;
      float lv = Ci[r] + base;
      if (r == 0 && ext0) lv += gv;
      bool msk = (j == 0) || (i > 0 && j == i);
      l[r][k] = msk ? -3.0e38f : lv;
      mx[r] = fmaxf(mx[r], l[r][k]);
    }
  }
  float lt[4] = {-3.0e38f, -3.0e38f, -3.0e38f, -3.0e38f};
  if (lane == 0) {
    float base = u_lds[256];
    float gv = ext0 ? g_lds[256] : 0.f;
    #pragma unroll
    for (int r = 0; r < 4; ++r) {
      int i = i0 + r;
      float lv = Ci[r] + base;
      if (r == 0 && ext0) lv += gv;
      lt[r] = (i == 256) ? -3.0e38f : lv;
      mx[r] = fmaxf(mx[r], lt[r]);
    }
  }
  #pragma unroll
  for (int r = 0; r < 4; ++r) mx[r] = wred_max(mx[r]);

  float pn[4][4];
  float s[4] = {0.f,0.f,0.f,0.f};
  #pragma unroll
  for (int r = 0; r < 4; ++r) {
    #pragma unroll
    for (int k = 0; k < 4; ++k) {
      float p = __expf(l[r][k] - mx[r]);
      pn[r][k] = p;
      s[r] += p;
    }
  }
  float pt[4] = {0.f,0.f,0.f,0.f};
  if (lane == 0) {
    #pragma unroll
    for (int r = 0; r < 4; ++r) { pt[r] = __expf(lt[r] - mx[r]); s[r] += pt[r]; }
  }
  float inv[4];
  #pragma unroll
  for (int r = 0; r < 4; ++r) inv[r] = 1.0f / wred_sum(s[r]);

  #pragma unroll
  for (int k = 0; k < 4; ++k) {
    int j = lane + 64*k;
    #pragma unroll
    for (int r = 0; r < 4; ++r) {
      pn[r][k] *= inv[r];
      if (valid[r]) out[ATT_BASE + (bh*TT + (i0+r))*TT + j] = pn[r][k];
    }
    p4_lds[wave][j] = make_float4(pn[0][k], pn[1][k], pn[2][k], pn[3][k]);
  }
  if (lane == 0) {
    float4 t4;
    float* tp = (float*)&t4;
    #pragma unroll
    for (int r = 0; r < 4; ++r) {
      tp[r] = pt[r] * inv[r];
      if (valid[r]) out[ATT_BASE + (bh*TT + (i0+r))*TT + 256] = tp[r];
    }
    p4_lds[wave][256] = t4;
  }
  if (lane >= 1 && lane < 16)
    p4_lds[wave][256 + lane] = make_float4(0.f,0.f,0.f,0.f);
  __syncthreads();

  int jjlo = lane >> 2, dq = lane & 3;
  float4 acc0 = {0,0,0,0}, acc1 = {0,0,0,0}, acc2 = {0,0,0,0}, acc3 = {0,0,0,0};
  #pragma unroll
  for (int it = 0; it < 17; ++it) {
    int jj = it*16 + jjlo;
    float4 v = v_lds[jj*4 + dq];
    float4 p = p4_lds[wave][jj];
    acc0.x += p.x*v.x; acc0.y += p.x*v.y; acc0.z += p.x*v.z; acc0.w += p.x*v.w;
    acc1.x += p.y*v.x; acc1.y += p.y*v.y; acc1.z += p.y*v.z; acc1.w += p.y*v.w;
    acc2.x += p.z*v.x; acc2.y += p.z*v.y; acc2.z += p.z*v.z; acc2.w += p.z*v.w;
    acc3.x += p.w*v.x; acc3.y += p.w*v.y; acc3.z += p.w*v.z; acc3.w += p.w*v.w;
  }
  float4 accs[4] = {acc0, acc1, acc2, acc3};
  #pragma unroll
  for (int r = 0; r < 4; ++r) {
    accs[r].x = red_jj(accs[r].x);
    accs[r].y = red_jj(accs[r].y);
    accs[r].z = red_jj(accs[r].z);
    accs[r].w = red_jj(accs[r].w);
  }
  if (lane < 4) {
    #pragma unroll
    for (int r = 0; r < 4; ++r) {
      if (valid[r])
        *(float4*)(out + ((b*TT + (i0+r))*NH + h)*HD + lane*4) = accs[r];
    }
  }
}

extern "C" void kernel_launch(void* const* d_in, const int* in_sizes, int n_in,
                              void* d_out, int out_size, void* d_ws, size_t ws_size,
                              hipStream_t stream) {
  const float* de  = (const float*)d_in[0];
  const float* nve = (const float*)d_in[1];
  const float* Wq  = (const float*)d_in[2];
  const float* bq  = (const float*)d_in[3];
  const float* Wk  = (const float*)d_in[4];
  const float* bk  = (const float*)d_in[5];
  const float* Wv  = (const float*)d_in[6];
  const float* bv  = (const float*)d_in[7];
  const float* aw  = (const float*)d_in[8];
  const float* ab  = (const float*)d_in[9];
  float* out = (float*)d_out;
  float* ws  = (float*)d_ws;

  setup_kernel<<<8, 256, 0, stream>>>(de, Wq, bq, Wk, bk, aw, ws);
  proj_kernel<<<(NPOS + 15)/16, 256, 0, stream>>>(nve, Wv, bv, ws);
  attn_kernel<<<32*17, 256, 0, stream>>>(ws, ab, out);
}